// Round 12
// baseline (256.959 us; speedup 1.0000x reference)
//
#include <hip/hip_runtime.h>
#include <math.h>

typedef unsigned short u16;
typedef unsigned int   u32;
typedef short  v8s __attribute__((ext_vector_type(8)));   // 8 bf16 = 4 VGPRs (MFMA A/B frag)
typedef float  v4f __attribute__((ext_vector_type(4)));   // MFMA C/D frag

constexpr int NB=2048, NN=60, DD=6, AF=37, BFD=6, HH=128, CC=12;
constexpr int T = 512;          // 8 waves
constexpr int FASTR = 168;      // A-buffer row stride (bf16); rows 0..63 = hi, 64..127 = lo
constexpr int XSTR  = 132;      // X-buffer row stride (fp32)
constexpr int KS1 = 2;          // conv1: K=43 -> 64
constexpr int KS2 = 5;          // conv2/gout: K=134 -> 160
constexpr int MAXP = 32;

// d_ws layout: 1KB fragment blocks per (d, ntile, kstep); hi table, lo mirror at LO_OFF.
constexpr int W1T_UNITS = 6*8*KS1;   // 96
constexpr int W2T_UNITS = 6*8*KS2;   // 240
constexpr int WOT_UNITS = 8*KS2;     // 40
constexpr int TOT_UNITS = W1T_UNITS + W2T_UNITS + WOT_UNITS;   // 376 x2 = 770 KB
constexpr int W2T_OFF = W1T_UNITS*512;
constexpr int WOT_OFF = (W1T_UNITS+W2T_UNITS)*512;
constexpr int LO_OFF  = TOT_UNITS*512;

__device__ __forceinline__ u16 f2bf(float f) {         // RNE fp32->bf16
  u32 u = __float_as_uint(f);
  return (u16)((u + 0x7FFFu + ((u >> 16) & 1u)) >> 16);
}
__device__ __forceinline__ float bf2f(u16 h) { return __uint_as_float((u32)h << 16); }

// split pair (a,b): hi = RNE bf16; lo = TRUNCATED residual bf16 (error 2^-17, cheap)
__device__ __forceinline__ void split2(float a, float b, u32& hi, u32& lo) {
  u16 ha = f2bf(a), hb = f2bf(b);
  u32 la = __float_as_uint(a - bf2f(ha)) >> 16;
  u32 lb = __float_as_uint(b - bf2f(hb)) >> 16;
  hi = ((u32)hb << 16) | ha;
  lo = (lb << 16) | la;
}
__device__ __forceinline__ void split8(const float* v, uint4& hi, uint4& lo) {
  split2(v[0], v[1], hi.x, lo.x); split2(v[2], v[3], hi.y, lo.y);
  split2(v[4], v[5], hi.z, lo.z); split2(v[6], v[7], hi.w, lo.w);
}
__device__ __forceinline__ float fast_tanh(float x) {
  float e = __expf(2.f * x);            // inf-safe
  return 1.f - 2.f / (e + 1.f);
}

// ---- prep: one 64-thread block per fragment unit (376 blocks). Lane l owns frag
// bytes l*16..+15; loads are 64B segments per 16 lanes; stores 16B/lane. ----
__global__ __launch_bounds__(64) void prep_kernel(
    const float* __restrict__ W1, const float* __restrict__ W2,
    const float* __restrict__ Wo, u16* __restrict__ ws)
{
  const int unit = blockIdx.x;
  if (unit >= TOT_UNITS) return;
  const int lane = threadIdx.x & 63;
  const int n16 = lane & 15, q = lane >> 4;
  const float* src; int K, nt, ks;
  if (unit < W1T_UNITS) {
    int d = unit / 16, rem = unit % 16; nt = rem >> 1; ks = rem & 1;
    src = W1 + (size_t)d*43*128; K = 43;
  } else if (unit < W1T_UNITS + W2T_UNITS) {
    int u = unit - W1T_UNITS; int d = u / 40, rem = u % 40; nt = rem / 5; ks = rem % 5;
    src = W2 + (size_t)d*134*128; K = 134;
  } else {
    int u = unit - (W1T_UNITS + W2T_UNITS); nt = u / 5; ks = u % 5;
    src = Wo; K = 134;
  }
  const int kbase = ks*32 + q*8;
  const int n = nt*16 + n16;
  float v8[8];
  #pragma unroll
  for (int j = 0; j < 8; ++j) {
    int k = kbase + j;
    v8[j] = (k < K) ? src[(size_t)k*128 + n] : 0.f;
  }
  uint4 H, L;
  split8(v8, H, L);
  ((uint4*)(ws + (size_t)unit*512))[lane] = H;
  ((uint4*)(ws + (size_t)(LO_OFF + unit*512)))[lane] = L;
}

// ---- conv via bf16x3 MFMA: wave owns a (degree, mtile) pair; A hi/lo in regs ----
template<int KSTEPS>
__device__ __forceinline__ void conv_mfma(
    const u16* __restrict__ wsW, const float* __restrict__ bias,
    const u16* sFA, float* sXout,
    const int* sSorted, const int* sDeg,
    const int* sPairD, const int* sPairM, int nP,
    int wv, int lane)
{
  const int n16 = lane & 15, q = lane >> 4;
  for (int p = wv; p < nP; p += 8) {
    const int d = sPairD[p], mt = sPairM[p];
    const int row = mt*16 + n16;
    int nodes[4];
    #pragma unroll
    for (int r = 0; r < 4; ++r) nodes[r] = sSorted[mt*16 + q*4 + r];
    if (d == 6) {                    // ref zeroes deg-6; degrees are 1..5 in practice
      #pragma unroll 1
      for (int nt = 0; nt < 8; ++nt) {
        const int h = nt*16 + n16;
        #pragma unroll
        for (int r = 0; r < 4; ++r)
          if (nodes[r] >= 0 && sDeg[nodes[r]] == 6) sXout[nodes[r]*XSTR + h] = 0.f;
      }
      continue;
    }
    v8s ah[KSTEPS], al[KSTEPS];
    #pragma unroll
    for (int ks = 0; ks < KSTEPS; ++ks) {
      ah[ks] = *(const v8s*)(&sFA[row*FASTR + ks*32 + q*8]);
      al[ks] = *(const v8s*)(&sFA[(64 + row)*FASTR + ks*32 + q*8]);
    }
    #pragma unroll 4
    for (int nt = 0; nt < 8; ++nt) {
      v4f acc = {0.f, 0.f, 0.f, 0.f};
      #pragma unroll
      for (int ks = 0; ks < KSTEPS; ++ks) {
        const size_t ub = ((size_t)((d*8 + nt)*KSTEPS + ks))*512;
        v8s bh = ((const v8s*)(wsW + ub))[lane];
        v8s bl = ((const v8s*)(wsW + LO_OFF + ub))[lane];
        acc = __builtin_amdgcn_mfma_f32_16x16x32_bf16(ah[ks], bh, acc, 0, 0, 0);
        acc = __builtin_amdgcn_mfma_f32_16x16x32_bf16(al[ks], bh, acc, 0, 0, 0);
        acc = __builtin_amdgcn_mfma_f32_16x16x32_bf16(ah[ks], bl, acc, 0, 0, 0);
      }
      const int h = nt*16 + n16;
      const float bb = bias[d*128 + h];
      #pragma unroll
      for (int r = 0; r < 4; ++r) {
        int node = nodes[r];
        if (node >= 0 && sDeg[node] == d)
          sXout[node*XSTR + h] = fmaxf(acc[r] + bb, 0.f);
      }
    }
  }
}

__global__ __launch_bounds__(T) void ngfp_kernel(
    const float* __restrict__ atoms, const float* __restrict__ bonds,
    const int*   __restrict__ edges,
    const float* __restrict__ b1, const float* __restrict__ b2,
    const float* __restrict__ bo,
    const float* __restrict__ Wfc, const float* __restrict__ bfc,
    const u16*   __restrict__ ws,
    float* __restrict__ out)
{
  __shared__ u16   sFA[128*FASTR];   // 43008 B — A-tiles hi (rows 0..63) + lo (64..127)
  __shared__ float sXa[NN*XSTR];     // 31680 B — atom staging / X1/X2/x3 (fp32)
  __shared__ float sBsum[NN*BFD];
  __shared__ int  sEdges[NN*DD];
  __shared__ int  sDeg[NN];
  __shared__ int  sSorted[64];
  __shared__ int  sRowStart[8];
  __shared__ int  sCnt[8];
  __shared__ int  sPairD[MAXP];
  __shared__ int  sPairM[MAXP];
  __shared__ int  sNP;
  __shared__ float sPart[HH];
  __shared__ float sRed[96];
  // total ~79.0 KB -> 2 blocks/CU, 16 waves/CU

  float* const sAtoms = sXa;   // compact stride-37 staging (odd stride: bank-friendly)

  const int b = blockIdx.x;
  const int t = threadIdx.x;
  const int wv = t >> 6;
  const int lane = t & 63;

  // ---- P0: stage edges, atoms, bond-sums; degree; sort; pair list ----
  for (int i = t; i < NN*DD; i += T) sEdges[i] = edges[b*NN*DD + i];
  for (int i = t; i < NN*AF; i += T) sAtoms[i] = atoms[b*NN*AF + i];
  for (int i = t; i < NN*BFD; i += T) {
    int n = i / BFD, f = i - n*BFD;
    const float* bp = bonds + ((size_t)(b*NN + n)*DD)*BFD + f;
    float s = 0.f;
    #pragma unroll
    for (int d = 0; d < DD; ++d) s += bp[d*BFD];
    sBsum[i] = s;
  }
  __syncthreads();
  if (t < NN) {
    int dg = 0;
    #pragma unroll
    for (int d = 0; d < DD; ++d) dg += (sEdges[t*DD + d] != -1) ? 1 : 0;
    sDeg[t] = dg;
  }
  __syncthreads();
  if (t < 7) {
    int c = 0;
    for (int n = 0; n < NN; ++n) c += (sDeg[n] == t) ? 1 : 0;
    sCnt[t] = c;
  }
  __syncthreads();
  if (t == 0) {
    int rs = 0;
    for (int d = 0; d < 7; ++d) { sRowStart[d] = rs; rs += sCnt[d]; }
    sRowStart[7] = rs;
    int np = 0;
    for (int d = 0; d < 7; ++d) {
      int r0 = sRowStart[d], r1 = sRowStart[d+1];
      if (r0 == r1) continue;
      for (int mt = r0 >> 4; mt < ((r1 + 15) >> 4); ++mt) {
        sPairD[np] = d; sPairM[np] = mt; ++np;
      }
    }
    sNP = np;
  }
  __syncthreads();
  if (t < 7) {
    int idx = sRowStart[t];
    for (int n = 0; n < NN; ++n) if (sDeg[n] == t) sSorted[idx++] = n;
  }
  if (t == 0) { sSorted[60] = sSorted[61] = sSorted[62] = sSorted[63] = -1; }
  __syncthreads();
  const int nP = sNP;

  // ---- P1: A1 build — scalar odd-stride-37 gathers (bank-spread), hi/lo out ----
  {
    const int row = t >> 3, c = t & 7;     // 512 units exactly
    const int node = sSorted[row];
    float acc[8] = {0,0,0,0,0,0,0,0};
    if (node >= 0) {
      int e[DD];
      #pragma unroll
      for (int d = 0; d < DD; ++d) e[d] = sEdges[node*DD + d];
      #pragma unroll
      for (int j = 0; j < 8; ++j) {
        int k = c*8 + j;
        float v = 0.f;
        if (k < AF) {
          v = sAtoms[node*AF + k];
          #pragma unroll
          for (int d = 0; d < DD; ++d) if (e[d] >= 0) v += sAtoms[e[d]*AF + k];
        } else if (k < AF + BFD) {
          v = sBsum[node*BFD + (k - AF)];
        }
        acc[j] = v;
      }
    }
    uint4 hi, lo; split8(acc, hi, lo);
    *(uint4*)(&sFA[row*FASTR + c*8]) = hi;
    *(uint4*)(&sFA[(64 + row)*FASTR + c*8]) = lo;
  }
  __syncthreads();

  // ---- P2: conv1 MFMA -> X1 (sXa fp32) ----
  conv_mfma<KS1>(ws, b1, sFA, sXa, sSorted, sDeg, sPairD, sPairM, nP, wv, lane);
  __syncthreads();

  // ---- P3: pool1 IN PLACE: X2 = max(self, nbrs)(X1) * (deg>0) ----
  {
    float4 m[4];
    #pragma unroll
    for (int j = 0; j < 4; ++j) {
      int idx = t + j*T;
      if (idx < NN*32) {
        int n = idx >> 5, c = idx & 31;
        float4 v = {0.f, 0.f, 0.f, 0.f};
        if (sDeg[n] > 0) {
          v = *(const float4*)(&sXa[n*XSTR + c*4]);
          #pragma unroll
          for (int d = 0; d < DD; ++d) {
            int e = sEdges[n*DD + d];
            if (e >= 0) {
              float4 u = *(const float4*)(&sXa[e*XSTR + c*4]);
              v.x = fmaxf(v.x, u.x); v.y = fmaxf(v.y, u.y);
              v.z = fmaxf(v.z, u.z); v.w = fmaxf(v.w, u.w);
            }
          }
        }
        m[j] = v;
      }
    }
    __syncthreads();
    #pragma unroll
    for (int j = 0; j < 4; ++j) {
      int idx = t + j*T;
      if (idx < NN*32) {
        int n = idx >> 5, c = idx & 31;
        *(float4*)(&sXa[n*XSTR + c*4]) = m[j];
      }
    }
  }
  __syncthreads();

  // ---- P4: A2 build — feat2 = (self+nbr sums of X2 | bsum | pad), hi/lo ----
  for (int unit = t; unit < 64*16; unit += T) {
    int row = unit >> 4, c = unit & 15;
    int node = sSorted[row];
    float acc[8] = {0,0,0,0,0,0,0,0};
    if (node >= 0) {
      *(float4*)(&acc[0]) = *(const float4*)(&sXa[node*XSTR + c*8]);
      *(float4*)(&acc[4]) = *(const float4*)(&sXa[node*XSTR + c*8 + 4]);
      #pragma unroll
      for (int d = 0; d < DD; ++d) {
        int e = sEdges[node*DD + d];
        if (e >= 0) {
          float4 u0 = *(const float4*)(&sXa[e*XSTR + c*8]);
          float4 u1 = *(const float4*)(&sXa[e*XSTR + c*8 + 4]);
          acc[0]+=u0.x; acc[1]+=u0.y; acc[2]+=u0.z; acc[3]+=u0.w;
          acc[4]+=u1.x; acc[5]+=u1.y; acc[6]+=u1.z; acc[7]+=u1.w;
        }
      }
    }
    uint4 hi, lo; split8(acc, hi, lo);
    *(uint4*)(&sFA[row*FASTR + c*8]) = hi;
    *(uint4*)(&sFA[(64 + row)*FASTR + c*8]) = lo;
  }
  // K-tail k=128..159 (bsum | zeros) — written ONCE here; P6 leaves it untouched,
  // so A3 (gout) reuses it (bsum is layer-invariant).
  if (t < 256) {
    int row = t >> 2, part = t & 3;
    uint4 hi = {0,0,0,0}, lo = {0,0,0,0};
    if (part == 0) {
      int node = sSorted[row];
      float acc[8] = {0,0,0,0,0,0,0,0};
      if (node >= 0) {
        #pragma unroll
        for (int j = 0; j < BFD; ++j) acc[j] = sBsum[node*BFD + j];
      }
      split8(acc, hi, lo);
    }
    *(uint4*)(&sFA[row*FASTR + 128 + part*8]) = hi;
    *(uint4*)(&sFA[(64 + row)*FASTR + 128 + part*8]) = lo;
  }
  __syncthreads();

  // ---- P5: conv2 MFMA -> x3 (sXa) ----
  conv_mfma<KS2>(ws + W2T_OFF, b2, sFA, sXa, sSorted, sDeg, sPairD, sPairM, nP, wv, lane);
  __syncthreads();

  // ---- P6+P7 FUSED: x4 = max(self,nbrs)(x3)*(deg>0) -> A3 hi/lo (cols 0..127 only) ----
  for (int unit = t; unit < 64*16; unit += T) {
    int row = unit >> 4, c = unit & 15;
    int node = sSorted[row];
    float acc[8] = {0,0,0,0,0,0,0,0};
    if (node >= 0 && sDeg[node] > 0) {
      float4 a0 = *(const float4*)(&sXa[node*XSTR + c*8]);
      float4 a1 = *(const float4*)(&sXa[node*XSTR + c*8 + 4]);
      #pragma unroll
      for (int d = 0; d < DD; ++d) {
        int e = sEdges[node*DD + d];
        if (e >= 0) {
          float4 u0 = *(const float4*)(&sXa[e*XSTR + c*8]);
          float4 u1 = *(const float4*)(&sXa[e*XSTR + c*8 + 4]);
          a0.x = fmaxf(a0.x, u0.x); a0.y = fmaxf(a0.y, u0.y);
          a0.z = fmaxf(a0.z, u0.z); a0.w = fmaxf(a0.w, u0.w);
          a1.x = fmaxf(a1.x, u1.x); a1.y = fmaxf(a1.y, u1.y);
          a1.z = fmaxf(a1.z, u1.z); a1.w = fmaxf(a1.w, u1.w);
        }
      }
      acc[0]=a0.x; acc[1]=a0.y; acc[2]=a0.z; acc[3]=a0.w;
      acc[4]=a1.x; acc[5]=a1.y; acc[6]=a1.z; acc[7]=a1.w;
    }
    uint4 hi, lo; split8(acc, hi, lo);
    *(uint4*)(&sFA[row*FASTR + c*8]) = hi;
    *(uint4*)(&sFA[(64 + row)*FASTR + c*8]) = lo;
  }
  __syncthreads();

  // ---- P8: gout MFMA: wave wv <-> n-tile wv; B hoisted to regs ----
  {
    const int nt = wv, n16 = lane & 15, q = lane >> 4;
    const int h = nt*16 + n16;
    v8s bh[KS2], bl[KS2];
    #pragma unroll
    for (int ks = 0; ks < KS2; ++ks) {
      const size_t ub = WOT_OFF + ((size_t)(nt*KS2 + ks))*512;
      bh[ks] = ((const v8s*)(ws + ub))[lane];
      bl[ks] = ((const v8s*)(ws + LO_OFF + ub))[lane];
    }
    const float bb = bo[h];
    float part = 0.f;
    #pragma unroll 2
    for (int mt = 0; mt < 4; ++mt) {
      const int row = mt*16 + n16;
      v4f acc = {0.f, 0.f, 0.f, 0.f};
      #pragma unroll
      for (int ks = 0; ks < KS2; ++ks) {
        v8s ah = *(const v8s*)(&sFA[row*FASTR + ks*32 + q*8]);
        v8s al = *(const v8s*)(&sFA[(64 + row)*FASTR + ks*32 + q*8]);
        acc = __builtin_amdgcn_mfma_f32_16x16x32_bf16(ah, bh[ks], acc, 0, 0, 0);
        acc = __builtin_amdgcn_mfma_f32_16x16x32_bf16(al, bh[ks], acc, 0, 0, 0);
        acc = __builtin_amdgcn_mfma_f32_16x16x32_bf16(ah, bl[ks], acc, 0, 0, 0);
      }
      #pragma unroll
      for (int r = 0; r < 4; ++r) {
        int node = sSorted[mt*16 + q*4 + r];
        if (node >= 0 && sDeg[node] > 0) part += fast_tanh(acc[r] + bb);
      }
    }
    part += __shfl_xor(part, 16);
    part += __shfl_xor(part, 32);
    if (lane < 16) sPart[h] = part;
  }
  __syncthreads();

  // ---- P9: final FC + sigmoid (96 threads, 16 FMAs each, reduce) ----
  if (t < 96) {
    const int c = t >> 3, s = t & 7;
    float acc = 0.f;
    #pragma unroll
    for (int i = 0; i < 16; ++i) {
      int ii = s*16 + i;
      acc = fmaf(sPart[ii], Wfc[ii*CC + c], acc);
    }
    sRed[t] = acc;
  }
  __syncthreads();
  if (t < CC) {
    float acc = bfc[t];
    #pragma unroll
    for (int s = 0; s < 8; ++s) acc += sRed[t*8 + s];
    out[b*CC + t] = 1.f / (1.f + __expf(-acc));
  }
}

extern "C" void kernel_launch(void* const* d_in, const int* in_sizes, int n_in,
                              void* d_out, int out_size, void* d_ws, size_t ws_size,
                              hipStream_t stream) {
  const float* atoms = (const float*)d_in[0];
  const float* bonds = (const float*)d_in[1];
  const int*   edges = (const int*)d_in[2];
  const float* W1  = (const float*)d_in[3];
  const float* b1  = (const float*)d_in[4];
  const float* W2  = (const float*)d_in[5];
  const float* b2  = (const float*)d_in[6];
  const float* Wo  = (const float*)d_in[7];
  const float* bo  = (const float*)d_in[8];
  const float* Wfc = (const float*)d_in[9];
  const float* bfc = (const float*)d_in[10];
  float* out = (float*)d_out;
  u16* ws = (u16*)d_ws;

  prep_kernel<<<TOT_UNITS, 64, 0, stream>>>(W1, W2, Wo, ws);
  ngfp_kernel<<<NB, T, 0, stream>>>(atoms, bonds, edges, b1, b2, bo, Wfc, bfc, ws, out);
}

// Round 13
// 246.031 us; speedup vs baseline: 1.0444x; 1.0444x over previous
//
#include <hip/hip_runtime.h>
#include <math.h>

typedef unsigned short u16;
typedef unsigned int   u32;
typedef unsigned long long u64;
typedef short  v8s __attribute__((ext_vector_type(8)));   // 8 bf16 = 4 VGPRs (MFMA A/B frag)
typedef float  v4f __attribute__((ext_vector_type(4)));   // MFMA C/D frag

constexpr int NB=2048, NN=60, DD=6, AF=37, BFD=6, HH=128, CC=12;
constexpr int T = 512;          // 8 waves
constexpr int FASTR = 168;      // A-buffer row stride (bf16); rows 0..63 = hi, 64..127 = lo
constexpr int XSTR  = 132;      // X-buffer row stride (fp32)
constexpr int KS1 = 2;          // conv1: K=43 -> 64
constexpr int KS2 = 5;          // conv2/gout: K=134 -> 160
constexpr int MAXP = 32;

// d_ws layout: 1KB fragment blocks per (d, ntile, kstep); hi table, lo mirror at LO_OFF.
constexpr int W1T_UNITS = 6*8*KS1;   // 96
constexpr int W2T_UNITS = 6*8*KS2;   // 240
constexpr int WOT_UNITS = 8*KS2;     // 40
constexpr int TOT_UNITS = W1T_UNITS + W2T_UNITS + WOT_UNITS;   // 376 x2 = 770 KB
constexpr int W2T_OFF = W1T_UNITS*512;
constexpr int WOT_OFF = (W1T_UNITS+W2T_UNITS)*512;
constexpr int LO_OFF  = TOT_UNITS*512;

__device__ __forceinline__ u16 f2bf(float f) {         // RNE fp32->bf16
  u32 u = __float_as_uint(f);
  return (u16)((u + 0x7FFFu + ((u >> 16) & 1u)) >> 16);
}
__device__ __forceinline__ float bf2f(u16 h) { return __uint_as_float((u32)h << 16); }

// split pair (a,b): hi = RNE bf16; lo = TRUNCATED residual bf16 (error 2^-17, cheap)
__device__ __forceinline__ void split2(float a, float b, u32& hi, u32& lo) {
  u16 ha = f2bf(a), hb = f2bf(b);
  u32 la = __float_as_uint(a - bf2f(ha)) >> 16;
  u32 lb = __float_as_uint(b - bf2f(hb)) >> 16;
  hi = ((u32)hb << 16) | ha;
  lo = (lb << 16) | la;
}
__device__ __forceinline__ void split8(const float* v, uint4& hi, uint4& lo) {
  split2(v[0], v[1], hi.x, lo.x); split2(v[2], v[3], hi.y, lo.y);
  split2(v[4], v[5], hi.z, lo.z); split2(v[6], v[7], hi.w, lo.w);
}
__device__ __forceinline__ float fast_tanh(float x) {
  float e = __expf(2.f * x);            // inf-safe
  return 1.f - 2.f / (e + 1.f);
}

// ---- prep: one 64-thread block per fragment unit (376 blocks) ----
__global__ __launch_bounds__(64) void prep_kernel(
    const float* __restrict__ W1, const float* __restrict__ W2,
    const float* __restrict__ Wo, u16* __restrict__ ws)
{
  const int unit = blockIdx.x;
  if (unit >= TOT_UNITS) return;
  const int lane = threadIdx.x & 63;
  const int n16 = lane & 15, q = lane >> 4;
  const float* src; int K, nt, ks;
  if (unit < W1T_UNITS) {
    int d = unit / 16, rem = unit % 16; nt = rem >> 1; ks = rem & 1;
    src = W1 + (size_t)d*43*128; K = 43;
  } else if (unit < W1T_UNITS + W2T_UNITS) {
    int u = unit - W1T_UNITS; int d = u / 40, rem = u % 40; nt = rem / 5; ks = rem % 5;
    src = W2 + (size_t)d*134*128; K = 134;
  } else {
    int u = unit - (W1T_UNITS + W2T_UNITS); nt = u / 5; ks = u % 5;
    src = Wo; K = 134;
  }
  const int kbase = ks*32 + q*8;
  const int n = nt*16 + n16;
  float v8[8];
  #pragma unroll
  for (int j = 0; j < 8; ++j) {
    int k = kbase + j;
    v8[j] = (k < K) ? src[(size_t)k*128 + n] : 0.f;
  }
  uint4 H, L;
  split8(v8, H, L);
  ((uint4*)(ws + (size_t)unit*512))[lane] = H;
  ((uint4*)(ws + (size_t)(LO_OFF + unit*512)))[lane] = L;
}

// ---- conv via bf16x3 MFMA. Work unit = (pair, nt-half): nP*2 units over 8 waves
// -> max wave load 1.5 pairs instead of 2 (conv time = max). A-frags re-read per
// half (cheap ds_read_b128 vs the 40 B-frag global loads per half). ----
template<int KSTEPS>
__device__ __forceinline__ void conv_mfma(
    const u16* __restrict__ wsW, const float* __restrict__ bias,
    const u16* sFA, float* sXout,
    const int* sSorted, const int* sDeg,
    const int* sPairD, const int* sPairM, int nP,
    int wv, int lane)
{
  const int n16 = lane & 15, q = lane >> 4;
  for (int u = wv; u < nP*2; u += 8) {
    const int p = u >> 1, nt0 = (u & 1) * 4;
    const int d = sPairD[p], mt = sPairM[p];
    const int row = mt*16 + n16;
    int nodes[4];
    #pragma unroll
    for (int r = 0; r < 4; ++r) nodes[r] = sSorted[mt*16 + q*4 + r];
    if (d == 6) {                    // ref zeroes deg-6; degrees are 1..5 in practice
      #pragma unroll 1
      for (int nt = nt0; nt < nt0+4; ++nt) {
        const int h = nt*16 + n16;
        #pragma unroll
        for (int r = 0; r < 4; ++r)
          if (nodes[r] >= 0 && sDeg[nodes[r]] == 6) sXout[nodes[r]*XSTR + h] = 0.f;
      }
      continue;
    }
    v8s ah[KSTEPS], al[KSTEPS];
    #pragma unroll
    for (int ks = 0; ks < KSTEPS; ++ks) {
      ah[ks] = *(const v8s*)(&sFA[row*FASTR + ks*32 + q*8]);
      al[ks] = *(const v8s*)(&sFA[(64 + row)*FASTR + ks*32 + q*8]);
    }
    #pragma unroll 4
    for (int nt = nt0; nt < nt0+4; ++nt) {
      v4f acc = {0.f, 0.f, 0.f, 0.f};
      #pragma unroll
      for (int ks = 0; ks < KSTEPS; ++ks) {
        const size_t ub = ((size_t)((d*8 + nt)*KSTEPS + ks))*512;
        v8s bh = ((const v8s*)(wsW + ub))[lane];
        v8s bl = ((const v8s*)(wsW + LO_OFF + ub))[lane];
        acc = __builtin_amdgcn_mfma_f32_16x16x32_bf16(ah[ks], bh, acc, 0, 0, 0);
        acc = __builtin_amdgcn_mfma_f32_16x16x32_bf16(al[ks], bh, acc, 0, 0, 0);
        acc = __builtin_amdgcn_mfma_f32_16x16x32_bf16(ah[ks], bl, acc, 0, 0, 0);
      }
      const int h = nt*16 + n16;
      const float bb = bias[d*128 + h];
      #pragma unroll
      for (int r = 0; r < 4; ++r) {
        int node = nodes[r];
        if (node >= 0 && sDeg[node] == d)
          sXout[node*XSTR + h] = fmaxf(acc[r] + bb, 0.f);
      }
    }
  }
}

__global__ __launch_bounds__(T) void ngfp_kernel(
    const float* __restrict__ atoms, const float* __restrict__ bonds,
    const int*   __restrict__ edges,
    const float* __restrict__ b1, const float* __restrict__ b2,
    const float* __restrict__ bo,
    const float* __restrict__ Wfc, const float* __restrict__ bfc,
    const u16*   __restrict__ ws,
    float* __restrict__ out)
{
  __shared__ u16   sFA[128*FASTR];   // 43008 B — A-tiles hi (rows 0..63) + lo (64..127)
  __shared__ float sXa[NN*XSTR];     // 31680 B — atom staging / X1/X2/x3 (fp32)
  __shared__ float sBsum[NN*BFD];
  __shared__ int  sEdges[NN*DD];
  __shared__ int  sDeg[NN];
  __shared__ int  sSorted[64];
  __shared__ int  sPairD[MAXP];
  __shared__ int  sPairM[MAXP];
  __shared__ int  sNP;
  __shared__ float sPart[HH];
  __shared__ float sRed[96];
  // total ~78.9 KB -> 2 blocks/CU, 16 waves/CU

  float* const sAtoms = sXa;   // compact stride-37 staging, dead once A1 built

  const int b = blockIdx.x;
  const int t = threadIdx.x;
  const int wv = t >> 6;
  const int lane = t & 63;

  // ---- P0: stage edges, atoms, bond-sums ----
  for (int i = t; i < NN*DD; i += T) sEdges[i] = edges[b*NN*DD + i];
  for (int i = t; i < NN*AF; i += T) sAtoms[i] = atoms[b*NN*AF + i];
  for (int i = t; i < NN*BFD; i += T) {
    int n = i / BFD, f = i - n*BFD;
    const float* bp = bonds + ((size_t)(b*NN + n)*DD)*BFD + f;
    float s = 0.f;
    #pragma unroll
    for (int d = 0; d < DD; ++d) s += bp[d*BFD];
    sBsum[i] = s;
  }
  __syncthreads();

  // ---- P0b: wave-0 ballot sort: degree, counting sort, pair list — ZERO extra
  // barriers (replaces 4-barrier serial sequence). ----
  if (wv == 0) {
    const int n = lane;                 // 0..63
    int dg = 7;                          // sentinel for pad lanes
    if (n < NN) {
      dg = 0;
      #pragma unroll
      for (int d = 0; d < DD; ++d) dg += (sEdges[n*DD + d] != -1) ? 1 : 0;
      sDeg[n] = dg;
    } else {
      sSorted[n] = -1;                   // pad entries 60..63
    }
    const u64 below = (lane == 63) ? ~0ull >> 1 : ((1ull << lane) - 1);
    int rs = 0, np = 0;
    #pragma unroll 1
    for (int d = 0; d < 7; ++d) {
      u64 m = __ballot(dg == d);
      int cnt = (int)__popcll(m);
      if (dg == d) sSorted[rs + (int)__popcll(m & below)] = n;
      if (lane == 0 && cnt > 0) {
        const int r1 = rs + cnt;
        for (int mt = rs >> 4; mt < ((r1 + 15) >> 4); ++mt) {
          sPairD[np] = d; sPairM[np] = mt; ++np;
        }
      }
      rs += cnt;
    }
    if (lane == 0) sNP = np;
  }
  __syncthreads();
  const int nP = sNP;

  // ---- P1: A1 build — scalar odd-stride-37 gathers, hi/lo out ----
  {
    const int row = t >> 3, c = t & 7;     // 512 units exactly
    const int node = sSorted[row];
    float acc[8] = {0,0,0,0,0,0,0,0};
    if (node >= 0) {
      int e[DD];
      #pragma unroll
      for (int d = 0; d < DD; ++d) e[d] = sEdges[node*DD + d];
      #pragma unroll
      for (int j = 0; j < 8; ++j) {
        int k = c*8 + j;
        float v = 0.f;
        if (k < AF) {
          v = sAtoms[node*AF + k];
          #pragma unroll
          for (int d = 0; d < DD; ++d) if (e[d] >= 0) v += sAtoms[e[d]*AF + k];
        } else if (k < AF + BFD) {
          v = sBsum[node*BFD + (k - AF)];
        }
        acc[j] = v;
      }
    }
    uint4 hi, lo; split8(acc, hi, lo);
    *(uint4*)(&sFA[row*FASTR + c*8]) = hi;
    *(uint4*)(&sFA[(64 + row)*FASTR + c*8]) = lo;
  }
  __syncthreads();

  // ---- P2: conv1 MFMA -> X1 (sXa fp32) ----
  conv_mfma<KS1>(ws, b1, sFA, sXa, sSorted, sDeg, sPairD, sPairM, nP, wv, lane);
  __syncthreads();

  // ---- P3: pool1 IN PLACE: X2 = max(self, nbrs)(X1) * (deg>0) ----
  {
    float4 m[4];
    #pragma unroll
    for (int j = 0; j < 4; ++j) {
      int idx = t + j*T;
      if (idx < NN*32) {
        int n = idx >> 5, c = idx & 31;
        float4 v = {0.f, 0.f, 0.f, 0.f};
        if (sDeg[n] > 0) {
          v = *(const float4*)(&sXa[n*XSTR + c*4]);
          #pragma unroll
          for (int d = 0; d < DD; ++d) {
            int e = sEdges[n*DD + d];
            if (e >= 0) {
              float4 u = *(const float4*)(&sXa[e*XSTR + c*4]);
              v.x = fmaxf(v.x, u.x); v.y = fmaxf(v.y, u.y);
              v.z = fmaxf(v.z, u.z); v.w = fmaxf(v.w, u.w);
            }
          }
        }
        m[j] = v;
      }
    }
    __syncthreads();
    #pragma unroll
    for (int j = 0; j < 4; ++j) {
      int idx = t + j*T;
      if (idx < NN*32) {
        int n = idx >> 5, c = idx & 31;
        *(float4*)(&sXa[n*XSTR + c*4]) = m[j];
      }
    }
  }
  __syncthreads();

  // ---- P4: A2 build — feat2 = (self+nbr sums of X2 | bsum | pad), hi/lo ----
  for (int unit = t; unit < 64*16; unit += T) {
    int row = unit >> 4, c = unit & 15;
    int node = sSorted[row];
    float acc[8] = {0,0,0,0,0,0,0,0};
    if (node >= 0) {
      *(float4*)(&acc[0]) = *(const float4*)(&sXa[node*XSTR + c*8]);
      *(float4*)(&acc[4]) = *(const float4*)(&sXa[node*XSTR + c*8 + 4]);
      #pragma unroll
      for (int d = 0; d < DD; ++d) {
        int e = sEdges[node*DD + d];
        if (e >= 0) {
          float4 u0 = *(const float4*)(&sXa[e*XSTR + c*8]);
          float4 u1 = *(const float4*)(&sXa[e*XSTR + c*8 + 4]);
          acc[0]+=u0.x; acc[1]+=u0.y; acc[2]+=u0.z; acc[3]+=u0.w;
          acc[4]+=u1.x; acc[5]+=u1.y; acc[6]+=u1.z; acc[7]+=u1.w;
        }
      }
    }
    uint4 hi, lo; split8(acc, hi, lo);
    *(uint4*)(&sFA[row*FASTR + c*8]) = hi;
    *(uint4*)(&sFA[(64 + row)*FASTR + c*8]) = lo;
  }
  // K-tail k=128..159 (bsum | zeros) — written ONCE; P6 leaves it untouched so
  // A3 (gout) reuses it (bsum is layer-invariant).
  if (t < 256) {
    int row = t >> 2, part = t & 3;
    uint4 hi = {0,0,0,0}, lo = {0,0,0,0};
    if (part == 0) {
      int node = sSorted[row];
      float acc[8] = {0,0,0,0,0,0,0,0};
      if (node >= 0) {
        #pragma unroll
        for (int j = 0; j < BFD; ++j) acc[j] = sBsum[node*BFD + j];
      }
      split8(acc, hi, lo);
    }
    *(uint4*)(&sFA[row*FASTR + 128 + part*8]) = hi;
    *(uint4*)(&sFA[(64 + row)*FASTR + 128 + part*8]) = lo;
  }
  __syncthreads();

  // ---- P5: conv2 MFMA -> x3 (sXa) ----
  conv_mfma<KS2>(ws + W2T_OFF, b2, sFA, sXa, sSorted, sDeg, sPairD, sPairM, nP, wv, lane);
  __syncthreads();

  // ---- P6+P7 FUSED: x4 = max(self,nbrs)(x3)*(deg>0) -> A3 hi/lo (cols 0..127) ----
  for (int unit = t; unit < 64*16; unit += T) {
    int row = unit >> 4, c = unit & 15;
    int node = sSorted[row];
    float acc[8] = {0,0,0,0,0,0,0,0};
    if (node >= 0 && sDeg[node] > 0) {
      float4 a0 = *(const float4*)(&sXa[node*XSTR + c*8]);
      float4 a1 = *(const float4*)(&sXa[node*XSTR + c*8 + 4]);
      #pragma unroll
      for (int d = 0; d < DD; ++d) {
        int e = sEdges[node*DD + d];
        if (e >= 0) {
          float4 u0 = *(const float4*)(&sXa[e*XSTR + c*8]);
          float4 u1 = *(const float4*)(&sXa[e*XSTR + c*8 + 4]);
          a0.x = fmaxf(a0.x, u0.x); a0.y = fmaxf(a0.y, u0.y);
          a0.z = fmaxf(a0.z, u0.z); a0.w = fmaxf(a0.w, u0.w);
          a1.x = fmaxf(a1.x, u1.x); a1.y = fmaxf(a1.y, u1.y);
          a1.z = fmaxf(a1.z, u1.z); a1.w = fmaxf(a1.w, u1.w);
        }
      }
      acc[0]=a0.x; acc[1]=a0.y; acc[2]=a0.z; acc[3]=a0.w;
      acc[4]=a1.x; acc[5]=a1.y; acc[6]=a1.z; acc[7]=a1.w;
    }
    uint4 hi, lo; split8(acc, hi, lo);
    *(uint4*)(&sFA[row*FASTR + c*8]) = hi;
    *(uint4*)(&sFA[(64 + row)*FASTR + c*8]) = lo;
  }
  __syncthreads();

  // ---- P8: gout MFMA: wave wv <-> n-tile wv; B hoisted to regs ----
  {
    const int nt = wv, n16 = lane & 15, q = lane >> 4;
    const int h = nt*16 + n16;
    v8s bh[KS2], bl[KS2];
    #pragma unroll
    for (int ks = 0; ks < KS2; ++ks) {
      const size_t ub = WOT_OFF + ((size_t)(nt*KS2 + ks))*512;
      bh[ks] = ((const v8s*)(ws + ub))[lane];
      bl[ks] = ((const v8s*)(ws + LO_OFF + ub))[lane];
    }
    const float bb = bo[h];
    float part = 0.f;
    #pragma unroll 2
    for (int mt = 0; mt < 4; ++mt) {
      const int row = mt*16 + n16;
      v4f acc = {0.f, 0.f, 0.f, 0.f};
      #pragma unroll
      for (int ks = 0; ks < KS2; ++ks) {
        v8s ah = *(const v8s*)(&sFA[row*FASTR + ks*32 + q*8]);
        v8s al = *(const v8s*)(&sFA[(64 + row)*FASTR + ks*32 + q*8]);
        acc = __builtin_amdgcn_mfma_f32_16x16x32_bf16(ah, bh[ks], acc, 0, 0, 0);
        acc = __builtin_amdgcn_mfma_f32_16x16x32_bf16(al, bh[ks], acc, 0, 0, 0);
        acc = __builtin_amdgcn_mfma_f32_16x16x32_bf16(ah, bl[ks], acc, 0, 0, 0);
      }
      #pragma unroll
      for (int r = 0; r < 4; ++r) {
        int node = sSorted[mt*16 + q*4 + r];
        if (node >= 0 && sDeg[node] > 0) part += fast_tanh(acc[r] + bb);
      }
    }
    part += __shfl_xor(part, 16);
    part += __shfl_xor(part, 32);
    if (lane < 16) sPart[h] = part;
  }
  __syncthreads();

  // ---- P9: final FC + sigmoid (96 threads, 16 FMAs each, reduce) ----
  if (t < 96) {
    const int c = t >> 3, s = t & 7;
    float acc = 0.f;
    #pragma unroll
    for (int i = 0; i < 16; ++i) {
      int ii = s*16 + i;
      acc = fmaf(sPart[ii], Wfc[ii*CC + c], acc);
    }
    sRed[t] = acc;
  }
  __syncthreads();
  if (t < CC) {
    float acc = bfc[t];
    #pragma unroll
    for (int s = 0; s < 8; ++s) acc += sRed[t*8 + s];
    out[b*CC + t] = 1.f / (1.f + __expf(-acc));
  }
}

extern "C" void kernel_launch(void* const* d_in, const int* in_sizes, int n_in,
                              void* d_out, int out_size, void* d_ws, size_t ws_size,
                              hipStream_t stream) {
  const float* atoms = (const float*)d_in[0];
  const float* bonds = (const float*)d_in[1];
  const int*   edges = (const int*)d_in[2];
  const float* W1  = (const float*)d_in[3];
  const float* b1  = (const float*)d_in[4];
  const float* W2  = (const float*)d_in[5];
  const float* b2  = (const float*)d_in[6];
  const float* Wo  = (const float*)d_in[7];
  const float* bo  = (const float*)d_in[8];
  const float* Wfc = (const float*)d_in[9];
  const float* bfc = (const float*)d_in[10];
  float* out = (float*)d_out;
  u16* ws = (u16*)d_ws;

  prep_kernel<<<TOT_UNITS, 64, 0, stream>>>(W1, W2, Wo, ws);
  ngfp_kernel<<<NB, T, 0, stream>>>(atoms, bonds, edges, b1, b2, bo, Wfc, bfc, ws, out);
}

// Round 14
// 245.686 us; speedup vs baseline: 1.0459x; 1.0014x over previous
//
#include <hip/hip_runtime.h>
#include <math.h>

typedef unsigned short u16;
typedef unsigned int   u32;
typedef unsigned long long u64;
typedef short  v8s __attribute__((ext_vector_type(8)));   // 8 bf16 = 4 VGPRs (MFMA A/B frag)
typedef float  v4f __attribute__((ext_vector_type(4)));   // MFMA C/D frag

constexpr int NB=2048, NN=60, DD=6, AF=37, BFD=6, HH=128, CC=12;
constexpr int T = 512;          // 8 waves
constexpr int FASTR = 168;      // A-buffer row stride (bf16); rows 0..63 = hi, 64..127 = lo
constexpr int XSTR  = 132;      // X-buffer row stride (fp32)
constexpr int KS1 = 2;          // conv1: K=43 -> 64
constexpr int KS2 = 5;          // conv2/gout: K=134 -> 160
constexpr int MAXP = 32;

// d_ws layout: 1KB fragment blocks per (d, ntile, kstep); hi table, lo mirror at LO_OFF.
constexpr int W1T_UNITS = 6*8*KS1;   // 96
constexpr int W2T_UNITS = 6*8*KS2;   // 240
constexpr int WOT_UNITS = 8*KS2;     // 40
constexpr int TOT_UNITS = W1T_UNITS + W2T_UNITS + WOT_UNITS;   // 376 x2 = 770 KB
constexpr int W2T_OFF = W1T_UNITS*512;
constexpr int WOT_OFF = (W1T_UNITS+W2T_UNITS)*512;
constexpr int LO_OFF  = TOT_UNITS*512;

__device__ __forceinline__ u16 f2bf(float f) {         // RNE fp32->bf16
  u32 u = __float_as_uint(f);
  return (u16)((u + 0x7FFFu + ((u >> 16) & 1u)) >> 16);
}
__device__ __forceinline__ float bf2f(u16 h) { return __uint_as_float((u32)h << 16); }

// split pair (a,b): hi = RNE bf16; lo = TRUNCATED residual bf16 (error 2^-17, cheap)
__device__ __forceinline__ void split2(float a, float b, u32& hi, u32& lo) {
  u16 ha = f2bf(a), hb = f2bf(b);
  u32 la = __float_as_uint(a - bf2f(ha)) >> 16;
  u32 lb = __float_as_uint(b - bf2f(hb)) >> 16;
  hi = ((u32)hb << 16) | ha;
  lo = (lb << 16) | la;
}
__device__ __forceinline__ void split8(const float* v, uint4& hi, uint4& lo) {
  split2(v[0], v[1], hi.x, lo.x); split2(v[2], v[3], hi.y, lo.y);
  split2(v[4], v[5], hi.z, lo.z); split2(v[6], v[7], hi.w, lo.w);
}
__device__ __forceinline__ float fast_tanh(float x) {
  float e = __expf(2.f * x);            // inf-safe
  return 1.f - 2.f / (e + 1.f);
}

// ---- prep (v1 shape: 753 blocks x 256 threads, one element/thread). Measured
// fastest end-to-end: big grid hides the strided-load latency; weights are
// L2/L3-resident so access pattern matters less than TLP. ----
__global__ __launch_bounds__(256) void prep_kernel(
    const float* __restrict__ W1, const float* __restrict__ W2,
    const float* __restrict__ Wo, u16* __restrict__ ws)
{
  int tid = blockIdx.x*256 + threadIdx.x;
  if (tid >= TOT_UNITS*512) return;
  int unit = tid >> 9, idx = tid & 511;
  int lane = idx >> 3, j = idx & 7;
  int n16 = lane & 15, q = lane >> 4;
  const float* src; int K, nt, ks;
  if (unit < W1T_UNITS) {
    int d = unit / 16, rem = unit % 16; nt = rem >> 1; ks = rem & 1;
    src = W1 + (size_t)d*43*128; K = 43;
  } else if (unit < W1T_UNITS + W2T_UNITS) {
    int u = unit - W1T_UNITS; int d = u / 40, rem = u % 40; nt = rem / 5; ks = rem % 5;
    src = W2 + (size_t)d*134*128; K = 134;
  } else {
    int u = unit - (W1T_UNITS + W2T_UNITS); nt = u / 5; ks = u % 5;
    src = Wo; K = 134;
  }
  int k = ks*32 + q*8 + j, n = nt*16 + n16;
  float v = (k < K) ? src[(size_t)k*128 + n] : 0.f;
  u16 hi = f2bf(v);
  u16 lo = (u16)(__float_as_uint(v - bf2f(hi)) >> 16);
  ws[(size_t)unit*512 + lane*8 + j] = hi;
  ws[(size_t)(LO_OFF + unit*512) + lane*8 + j] = lo;
}

// ---- conv via bf16x3 MFMA. Work unit = (pair, nt-half): nP*2 units over 8 waves
// -> max wave load 1.5 pairs instead of 2 (conv time = max). ----
template<int KSTEPS>
__device__ __forceinline__ void conv_mfma(
    const u16* __restrict__ wsW, const float* __restrict__ bias,
    const u16* sFA, float* sXout,
    const int* sSorted, const int* sDeg,
    const int* sPairD, const int* sPairM, int nP,
    int wv, int lane)
{
  const int n16 = lane & 15, q = lane >> 4;
  for (int u = wv; u < nP*2; u += 8) {
    const int p = u >> 1, nt0 = (u & 1) * 4;
    const int d = sPairD[p], mt = sPairM[p];
    const int row = mt*16 + n16;
    int nodes[4];
    #pragma unroll
    for (int r = 0; r < 4; ++r) nodes[r] = sSorted[mt*16 + q*4 + r];
    if (d == 6) {                    // ref zeroes deg-6; degrees are 1..5 in practice
      #pragma unroll 1
      for (int nt = nt0; nt < nt0+4; ++nt) {
        const int h = nt*16 + n16;
        #pragma unroll
        for (int r = 0; r < 4; ++r)
          if (nodes[r] >= 0 && sDeg[nodes[r]] == 6) sXout[nodes[r]*XSTR + h] = 0.f;
      }
      continue;
    }
    v8s ah[KSTEPS], al[KSTEPS];
    #pragma unroll
    for (int ks = 0; ks < KSTEPS; ++ks) {
      ah[ks] = *(const v8s*)(&sFA[row*FASTR + ks*32 + q*8]);
      al[ks] = *(const v8s*)(&sFA[(64 + row)*FASTR + ks*32 + q*8]);
    }
    #pragma unroll 4
    for (int nt = nt0; nt < nt0+4; ++nt) {
      v4f acc = {0.f, 0.f, 0.f, 0.f};
      #pragma unroll
      for (int ks = 0; ks < KSTEPS; ++ks) {
        const size_t ub = ((size_t)((d*8 + nt)*KSTEPS + ks))*512;
        v8s bh = ((const v8s*)(wsW + ub))[lane];
        v8s bl = ((const v8s*)(wsW + LO_OFF + ub))[lane];
        acc = __builtin_amdgcn_mfma_f32_16x16x32_bf16(ah[ks], bh, acc, 0, 0, 0);
        acc = __builtin_amdgcn_mfma_f32_16x16x32_bf16(al[ks], bh, acc, 0, 0, 0);
        acc = __builtin_amdgcn_mfma_f32_16x16x32_bf16(ah[ks], bl, acc, 0, 0, 0);
      }
      const int h = nt*16 + n16;
      const float bb = bias[d*128 + h];
      #pragma unroll
      for (int r = 0; r < 4; ++r) {
        int node = nodes[r];
        if (node >= 0 && sDeg[node] == d)
          sXout[node*XSTR + h] = fmaxf(acc[r] + bb, 0.f);
      }
    }
  }
}

__global__ __launch_bounds__(T) void ngfp_kernel(
    const float* __restrict__ atoms, const float* __restrict__ bonds,
    const int*   __restrict__ edges,
    const float* __restrict__ b1, const float* __restrict__ b2,
    const float* __restrict__ bo,
    const float* __restrict__ Wfc, const float* __restrict__ bfc,
    const u16*   __restrict__ ws,
    float* __restrict__ out)
{
  __shared__ u16   sFA[128*FASTR];   // 43008 B — A-tiles hi (rows 0..63) + lo (64..127)
  __shared__ float sXa[NN*XSTR];     // 31680 B — atom staging / X1/X2/x3 (fp32)
  __shared__ float sBsum[NN*BFD];
  __shared__ int  sEdges[NN*DD];
  __shared__ int  sDeg[NN];
  __shared__ int  sSorted[64];
  __shared__ int  sPairD[MAXP];
  __shared__ int  sPairM[MAXP];
  __shared__ int  sNP;
  __shared__ float sPart[HH];
  __shared__ float sRed[96];
  // total ~78.9 KB -> 2 blocks/CU, 16 waves/CU

  float* const sAtoms = sXa;   // compact stride-37 staging, dead once A1 built

  const int b = blockIdx.x;
  const int t = threadIdx.x;
  const int wv = t >> 6;
  const int lane = t & 63;

  // ---- P0: stage edges, atoms, bond-sums ----
  for (int i = t; i < NN*DD; i += T) sEdges[i] = edges[b*NN*DD + i];
  for (int i = t; i < NN*AF; i += T) sAtoms[i] = atoms[b*NN*AF + i];
  for (int i = t; i < NN*BFD; i += T) {
    int n = i / BFD, f = i - n*BFD;
    const float* bp = bonds + ((size_t)(b*NN + n)*DD)*BFD + f;
    float s = 0.f;
    #pragma unroll
    for (int d = 0; d < DD; ++d) s += bp[d*BFD];
    sBsum[i] = s;
  }
  __syncthreads();

  // ---- P0b: wave-0 ballot sort: degree, counting sort, pair list ----
  if (wv == 0) {
    const int n = lane;                 // 0..63
    int dg = 7;                          // sentinel for pad lanes
    if (n < NN) {
      dg = 0;
      #pragma unroll
      for (int d = 0; d < DD; ++d) dg += (sEdges[n*DD + d] != -1) ? 1 : 0;
      sDeg[n] = dg;
    } else {
      sSorted[n] = -1;                   // pad entries 60..63
    }
    const u64 below = (lane == 63) ? ~0ull >> 1 : ((1ull << lane) - 1);
    int rs = 0, np = 0;
    #pragma unroll 1
    for (int d = 0; d < 7; ++d) {
      u64 m = __ballot(dg == d);
      int cnt = (int)__popcll(m);
      if (dg == d) sSorted[rs + (int)__popcll(m & below)] = n;
      if (lane == 0 && cnt > 0) {
        const int r1 = rs + cnt;
        for (int mt = rs >> 4; mt < ((r1 + 15) >> 4); ++mt) {
          sPairD[np] = d; sPairM[np] = mt; ++np;
        }
      }
      rs += cnt;
    }
    if (lane == 0) sNP = np;
  }
  __syncthreads();
  const int nP = sNP;

  // ---- P1: A1 build — scalar odd-stride-37 gathers, hi/lo out ----
  {
    const int row = t >> 3, c = t & 7;     // 512 units exactly
    const int node = sSorted[row];
    float acc[8] = {0,0,0,0,0,0,0,0};
    if (node >= 0) {
      int e[DD];
      #pragma unroll
      for (int d = 0; d < DD; ++d) e[d] = sEdges[node*DD + d];
      #pragma unroll
      for (int j = 0; j < 8; ++j) {
        int k = c*8 + j;
        float v = 0.f;
        if (k < AF) {
          v = sAtoms[node*AF + k];
          #pragma unroll
          for (int d = 0; d < DD; ++d) if (e[d] >= 0) v += sAtoms[e[d]*AF + k];
        } else if (k < AF + BFD) {
          v = sBsum[node*BFD + (k - AF)];
        }
        acc[j] = v;
      }
    }
    uint4 hi, lo; split8(acc, hi, lo);
    *(uint4*)(&sFA[row*FASTR + c*8]) = hi;
    *(uint4*)(&sFA[(64 + row)*FASTR + c*8]) = lo;
  }
  __syncthreads();

  // ---- P2: conv1 MFMA -> X1 (sXa fp32) ----
  conv_mfma<KS1>(ws, b1, sFA, sXa, sSorted, sDeg, sPairD, sPairM, nP, wv, lane);
  __syncthreads();

  // ---- P3: pool1 IN PLACE: X2 = max(self, nbrs)(X1) * (deg>0) ----
  {
    float4 m[4];
    #pragma unroll
    for (int j = 0; j < 4; ++j) {
      int idx = t + j*T;
      if (idx < NN*32) {
        int n = idx >> 5, c = idx & 31;
        float4 v = {0.f, 0.f, 0.f, 0.f};
        if (sDeg[n] > 0) {
          v = *(const float4*)(&sXa[n*XSTR + c*4]);
          #pragma unroll
          for (int d = 0; d < DD; ++d) {
            int e = sEdges[n*DD + d];
            if (e >= 0) {
              float4 u = *(const float4*)(&sXa[e*XSTR + c*4]);
              v.x = fmaxf(v.x, u.x); v.y = fmaxf(v.y, u.y);
              v.z = fmaxf(v.z, u.z); v.w = fmaxf(v.w, u.w);
            }
          }
        }
        m[j] = v;
      }
    }
    __syncthreads();
    #pragma unroll
    for (int j = 0; j < 4; ++j) {
      int idx = t + j*T;
      if (idx < NN*32) {
        int n = idx >> 5, c = idx & 31;
        *(float4*)(&sXa[n*XSTR + c*4]) = m[j];
      }
    }
  }
  __syncthreads();

  // ---- P4: A2 build — feat2 = (self+nbr sums of X2 | bsum | pad), hi/lo ----
  for (int unit = t; unit < 64*16; unit += T) {
    int row = unit >> 4, c = unit & 15;
    int node = sSorted[row];
    float acc[8] = {0,0,0,0,0,0,0,0};
    if (node >= 0) {
      *(float4*)(&acc[0]) = *(const float4*)(&sXa[node*XSTR + c*8]);
      *(float4*)(&acc[4]) = *(const float4*)(&sXa[node*XSTR + c*8 + 4]);
      #pragma unroll
      for (int d = 0; d < DD; ++d) {
        int e = sEdges[node*DD + d];
        if (e >= 0) {
          float4 u0 = *(const float4*)(&sXa[e*XSTR + c*8]);
          float4 u1 = *(const float4*)(&sXa[e*XSTR + c*8 + 4]);
          acc[0]+=u0.x; acc[1]+=u0.y; acc[2]+=u0.z; acc[3]+=u0.w;
          acc[4]+=u1.x; acc[5]+=u1.y; acc[6]+=u1.z; acc[7]+=u1.w;
        }
      }
    }
    uint4 hi, lo; split8(acc, hi, lo);
    *(uint4*)(&sFA[row*FASTR + c*8]) = hi;
    *(uint4*)(&sFA[(64 + row)*FASTR + c*8]) = lo;
  }
  // K-tail k=128..159 (bsum | zeros) — written ONCE; P6 leaves it untouched so
  // A3 (gout) reuses it (bsum is layer-invariant).
  if (t < 256) {
    int row = t >> 2, part = t & 3;
    uint4 hi = {0,0,0,0}, lo = {0,0,0,0};
    if (part == 0) {
      int node = sSorted[row];
      float acc[8] = {0,0,0,0,0,0,0,0};
      if (node >= 0) {
        #pragma unroll
        for (int j = 0; j < BFD; ++j) acc[j] = sBsum[node*BFD + j];
      }
      split8(acc, hi, lo);
    }
    *(uint4*)(&sFA[row*FASTR + 128 + part*8]) = hi;
    *(uint4*)(&sFA[(64 + row)*FASTR + 128 + part*8]) = lo;
  }
  __syncthreads();

  // ---- P5: conv2 MFMA -> x3 (sXa) ----
  conv_mfma<KS2>(ws + W2T_OFF, b2, sFA, sXa, sSorted, sDeg, sPairD, sPairM, nP, wv, lane);
  __syncthreads();

  // ---- P6+P7 FUSED: x4 = max(self,nbrs)(x3)*(deg>0) -> A3 hi/lo (cols 0..127) ----
  for (int unit = t; unit < 64*16; unit += T) {
    int row = unit >> 4, c = unit & 15;
    int node = sSorted[row];
    float acc[8] = {0,0,0,0,0,0,0,0};
    if (node >= 0 && sDeg[node] > 0) {
      float4 a0 = *(const float4*)(&sXa[node*XSTR + c*8]);
      float4 a1 = *(const float4*)(&sXa[node*XSTR + c*8 + 4]);
      #pragma unroll
      for (int d = 0; d < DD; ++d) {
        int e = sEdges[node*DD + d];
        if (e >= 0) {
          float4 u0 = *(const float4*)(&sXa[e*XSTR + c*8]);
          float4 u1 = *(const float4*)(&sXa[e*XSTR + c*8 + 4]);
          a0.x = fmaxf(a0.x, u0.x); a0.y = fmaxf(a0.y, u0.y);
          a0.z = fmaxf(a0.z, u0.z); a0.w = fmaxf(a0.w, u0.w);
          a1.x = fmaxf(a1.x, u1.x); a1.y = fmaxf(a1.y, u1.y);
          a1.z = fmaxf(a1.z, u1.z); a1.w = fmaxf(a1.w, u1.w);
        }
      }
      acc[0]=a0.x; acc[1]=a0.y; acc[2]=a0.z; acc[3]=a0.w;
      acc[4]=a1.x; acc[5]=a1.y; acc[6]=a1.z; acc[7]=a1.w;
    }
    uint4 hi, lo; split8(acc, hi, lo);
    *(uint4*)(&sFA[row*FASTR + c*8]) = hi;
    *(uint4*)(&sFA[(64 + row)*FASTR + c*8]) = lo;
  }
  __syncthreads();

  // ---- P8: gout MFMA: wave wv <-> n-tile wv; B hoisted to regs ----
  {
    const int nt = wv, n16 = lane & 15, q = lane >> 4;
    const int h = nt*16 + n16;
    v8s bh[KS2], bl[KS2];
    #pragma unroll
    for (int ks = 0; ks < KS2; ++ks) {
      const size_t ub = WOT_OFF + ((size_t)(nt*KS2 + ks))*512;
      bh[ks] = ((const v8s*)(ws + ub))[lane];
      bl[ks] = ((const v8s*)(ws + LO_OFF + ub))[lane];
    }
    const float bb = bo[h];
    float part = 0.f;
    #pragma unroll 2
    for (int mt = 0; mt < 4; ++mt) {
      const int row = mt*16 + n16;
      v4f acc = {0.f, 0.f, 0.f, 0.f};
      #pragma unroll
      for (int ks = 0; ks < KS2; ++ks) {
        v8s ah = *(const v8s*)(&sFA[row*FASTR + ks*32 + q*8]);
        v8s al = *(const v8s*)(&sFA[(64 + row)*FASTR + ks*32 + q*8]);
        acc = __builtin_amdgcn_mfma_f32_16x16x32_bf16(ah, bh[ks], acc, 0, 0, 0);
        acc = __builtin_amdgcn_mfma_f32_16x16x32_bf16(al, bh[ks], acc, 0, 0, 0);
        acc = __builtin_amdgcn_mfma_f32_16x16x32_bf16(ah, bl[ks], acc, 0, 0, 0);
      }
      #pragma unroll
      for (int r = 0; r < 4; ++r) {
        int node = sSorted[mt*16 + q*4 + r];
        if (node >= 0 && sDeg[node] > 0) part += fast_tanh(acc[r] + bb);
      }
    }
    part += __shfl_xor(part, 16);
    part += __shfl_xor(part, 32);
    if (lane < 16) sPart[h] = part;
  }
  __syncthreads();

  // ---- P9: final FC + sigmoid (96 threads, 16 FMAs each, reduce) ----
  if (t < 96) {
    const int c = t >> 3, s = t & 7;
    float acc = 0.f;
    #pragma unroll
    for (int i = 0; i < 16; ++i) {
      int ii = s*16 + i;
      acc = fmaf(sPart[ii], Wfc[ii*CC + c], acc);
    }
    sRed[t] = acc;
  }
  __syncthreads();
  if (t < CC) {
    float acc = bfc[t];
    #pragma unroll
    for (int s = 0; s < 8; ++s) acc += sRed[t*8 + s];
    out[b*CC + t] = 1.f / (1.f + __expf(-acc));
  }
}

extern "C" void kernel_launch(void* const* d_in, const int* in_sizes, int n_in,
                              void* d_out, int out_size, void* d_ws, size_t ws_size,
                              hipStream_t stream) {
  const float* atoms = (const float*)d_in[0];
  const float* bonds = (const float*)d_in[1];
  const int*   edges = (const int*)d_in[2];
  const float* W1  = (const float*)d_in[3];
  const float* b1  = (const float*)d_in[4];
  const float* W2  = (const float*)d_in[5];
  const float* b2  = (const float*)d_in[6];
  const float* Wo  = (const float*)d_in[7];
  const float* bo  = (const float*)d_in[8];
  const float* Wfc = (const float*)d_in[9];
  const float* bfc = (const float*)d_in[10];
  float* out = (float*)d_out;
  u16* ws = (u16*)d_ws;

  prep_kernel<<<(TOT_UNITS*512 + 255)/256, 256, 0, stream>>>(W1, W2, Wo, ws);
  ngfp_kernel<<<NB, T, 0, stream>>>(atoms, bonds, edges, b1, b2, bo, Wfc, bfc, ws, out);
}

// Round 15
// 242.788 us; speedup vs baseline: 1.0584x; 1.0119x over previous
//
#include <hip/hip_runtime.h>
#include <math.h>

typedef unsigned short u16;
typedef unsigned int   u32;
typedef unsigned long long u64;
typedef short  v8s __attribute__((ext_vector_type(8)));   // 8 bf16 = 4 VGPRs (MFMA A/B frag)
typedef float  v4f __attribute__((ext_vector_type(4)));   // MFMA C/D frag

constexpr int NB=2048, NN=60, DD=6, AF=37, BFD=6, HH=128, CC=12;
constexpr int T = 512;          // 8 waves
constexpr int FASTR = 168;      // A-buffer row stride (bf16); rows 0..63 = hi, 64..127 = lo
constexpr int XSTR  = 132;      // X-buffer row stride (fp32)
constexpr int KS1 = 2;          // conv1: K=43 -> 64
constexpr int KS2 = 5;          // conv2/gout: K=134 -> 160
constexpr int MAXP = 32;

// d_ws layout: 1KB fragment blocks per (d, ntile, kstep); hi table, lo mirror at LO_OFF.
constexpr int W1T_UNITS = 6*8*KS1;   // 96
constexpr int W2T_UNITS = 6*8*KS2;   // 240
constexpr int WOT_UNITS = 8*KS2;     // 40
constexpr int TOT_UNITS = W1T_UNITS + W2T_UNITS + WOT_UNITS;   // 376 x2 = 770 KB
constexpr int W2T_OFF = W1T_UNITS*512;
constexpr int WOT_OFF = (W1T_UNITS+W2T_UNITS)*512;
constexpr int LO_OFF  = TOT_UNITS*512;

__device__ __forceinline__ u16 f2bf(float f) {         // RNE fp32->bf16
  u32 u = __float_as_uint(f);
  return (u16)((u + 0x7FFFu + ((u >> 16) & 1u)) >> 16);
}
__device__ __forceinline__ float bf2f(u16 h) { return __uint_as_float((u32)h << 16); }

// split pair (a,b): hi = RNE bf16; lo = TRUNCATED residual bf16 (error 2^-17, cheap)
__device__ __forceinline__ void split2(float a, float b, u32& hi, u32& lo) {
  u16 ha = f2bf(a), hb = f2bf(b);
  u32 la = __float_as_uint(a - bf2f(ha)) >> 16;
  u32 lb = __float_as_uint(b - bf2f(hb)) >> 16;
  hi = ((u32)hb << 16) | ha;
  lo = (lb << 16) | la;
}
__device__ __forceinline__ void split8(const float* v, uint4& hi, uint4& lo) {
  split2(v[0], v[1], hi.x, lo.x); split2(v[2], v[3], hi.y, lo.y);
  split2(v[4], v[5], hi.z, lo.z); split2(v[6], v[7], hi.w, lo.w);
}
__device__ __forceinline__ float fast_tanh(float x) {
  float e = __expf(2.f * x);            // inf-safe
  return 1.f - 2.f / (e + 1.f);
}

// ---- prep: 753 blocks x 256 threads, one element/thread (prep shape is
// overhead-neutral per R9/R13/R14 A/B; keep the simple one) ----
__global__ __launch_bounds__(256) void prep_kernel(
    const float* __restrict__ W1, const float* __restrict__ W2,
    const float* __restrict__ Wo, u16* __restrict__ ws)
{
  int tid = blockIdx.x*256 + threadIdx.x;
  if (tid >= TOT_UNITS*512) return;
  int unit = tid >> 9, idx = tid & 511;
  int lane = idx >> 3, j = idx & 7;
  int n16 = lane & 15, q = lane >> 4;
  const float* src; int K, nt, ks;
  if (unit < W1T_UNITS) {
    int d = unit / 16, rem = unit % 16; nt = rem >> 1; ks = rem & 1;
    src = W1 + (size_t)d*43*128; K = 43;
  } else if (unit < W1T_UNITS + W2T_UNITS) {
    int u = unit - W1T_UNITS; int d = u / 40, rem = u % 40; nt = rem / 5; ks = rem % 5;
    src = W2 + (size_t)d*134*128; K = 134;
  } else {
    int u = unit - (W1T_UNITS + W2T_UNITS); nt = u / 5; ks = u % 5;
    src = Wo; K = 134;
  }
  int k = ks*32 + q*8 + j, n = nt*16 + n16;
  float v = (k < K) ? src[(size_t)k*128 + n] : 0.f;
  u16 hi = f2bf(v);
  u16 lo = (u16)(__float_as_uint(v - bf2f(hi)) >> 16);
  ws[(size_t)unit*512 + lane*8 + j] = hi;
  ws[(size_t)(LO_OFF + unit*512) + lane*8 + j] = lo;
}

// ---- conv via bf16x3 MFMA. Work unit = (pair, nt-QUARTER): nP*4 units over 8
// waves -> max wave load 1.25 pairs (was 1.5 with halves). ----
template<int KSTEPS>
__device__ __forceinline__ void conv_mfma(
    const u16* __restrict__ wsW, const float* __restrict__ bias,
    const u16* sFA, float* sXout,
    const int* sSorted, const int* sDeg,
    const int* sPairD, const int* sPairM, int nP,
    int wv, int lane)
{
  const int n16 = lane & 15, q = lane >> 4;
  for (int u = wv; u < nP*4; u += 8) {
    const int p = u >> 2, nt0 = (u & 3) * 2;
    const int d = sPairD[p], mt = sPairM[p];
    const int row = mt*16 + n16;
    int nodes[4];
    #pragma unroll
    for (int r = 0; r < 4; ++r) nodes[r] = sSorted[mt*16 + q*4 + r];
    if (d == 6) {                    // ref zeroes deg-6; degrees are 1..5 in practice
      #pragma unroll 1
      for (int nt = nt0; nt < nt0+2; ++nt) {
        const int h = nt*16 + n16;
        #pragma unroll
        for (int r = 0; r < 4; ++r)
          if (nodes[r] >= 0 && sDeg[nodes[r]] == 6) sXout[nodes[r]*XSTR + h] = 0.f;
      }
      continue;
    }
    v8s ah[KSTEPS], al[KSTEPS];
    #pragma unroll
    for (int ks = 0; ks < KSTEPS; ++ks) {
      ah[ks] = *(const v8s*)(&sFA[row*FASTR + ks*32 + q*8]);
      al[ks] = *(const v8s*)(&sFA[(64 + row)*FASTR + ks*32 + q*8]);
    }
    #pragma unroll
    for (int nt = nt0; nt < nt0+2; ++nt) {
      v4f acc = {0.f, 0.f, 0.f, 0.f};
      #pragma unroll
      for (int ks = 0; ks < KSTEPS; ++ks) {
        const size_t ub = ((size_t)((d*8 + nt)*KSTEPS + ks))*512;
        v8s bh = ((const v8s*)(wsW + ub))[lane];
        v8s bl = ((const v8s*)(wsW + LO_OFF + ub))[lane];
        acc = __builtin_amdgcn_mfma_f32_16x16x32_bf16(ah[ks], bh, acc, 0, 0, 0);
        acc = __builtin_amdgcn_mfma_f32_16x16x32_bf16(al[ks], bh, acc, 0, 0, 0);
        acc = __builtin_amdgcn_mfma_f32_16x16x32_bf16(ah[ks], bl, acc, 0, 0, 0);
      }
      const int h = nt*16 + n16;
      const float bb = bias[d*128 + h];
      #pragma unroll
      for (int r = 0; r < 4; ++r) {
        int node = nodes[r];
        if (node >= 0 && sDeg[node] == d)
          sXout[node*XSTR + h] = fmaxf(acc[r] + bb, 0.f);
      }
    }
  }
}

__global__ __launch_bounds__(T) void ngfp_kernel(
    const float* __restrict__ atoms, const float* __restrict__ bonds,
    const int*   __restrict__ edges,
    const float* __restrict__ b1, const float* __restrict__ b2,
    const float* __restrict__ bo,
    const float* __restrict__ Wfc, const float* __restrict__ bfc,
    const u16*   __restrict__ ws,
    float* __restrict__ out)
{
  __shared__ u16   sFA[128*FASTR];   // 43008 B — A-tiles hi (rows 0..63) + lo (64..127)
  __shared__ float sXa[NN*XSTR];     // 31680 B — atom staging / X1/X2/x3 (fp32)
  __shared__ float sBsum[NN*BFD];
  __shared__ int  sEdges[NN*DD];
  __shared__ int  sDeg[NN];
  __shared__ int  sSorted[64];
  __shared__ int  sPairD[MAXP];
  __shared__ int  sPairM[MAXP];
  __shared__ int  sNP;
  __shared__ float sPart[HH];
  __shared__ float sRed[96];
  // total ~78.9 KB -> 2 blocks/CU, 16 waves/CU

  float* const sAtoms = sXa;   // compact stride-37 staging, dead once A1 built

  const int b = blockIdx.x;
  const int t = threadIdx.x;
  const int wv = t >> 6;
  const int lane = t & 63;

  // ---- P0: stage edges, atoms, bond-sums ----
  for (int i = t; i < NN*DD; i += T) sEdges[i] = edges[b*NN*DD + i];
  for (int i = t; i < NN*AF; i += T) sAtoms[i] = atoms[b*NN*AF + i];
  for (int i = t; i < NN*BFD; i += T) {
    int n = i / BFD, f = i - n*BFD;
    const float* bp = bonds + ((size_t)(b*NN + n)*DD)*BFD + f;
    float s = 0.f;
    #pragma unroll
    for (int d = 0; d < DD; ++d) s += bp[d*BFD];
    sBsum[i] = s;
  }
  __syncthreads();

  // ---- P0b: wave-0 ballot sort: degree, counting sort, pair list ----
  if (wv == 0) {
    const int n = lane;                 // 0..63
    int dg = 7;                          // sentinel for pad lanes
    if (n < NN) {
      dg = 0;
      #pragma unroll
      for (int d = 0; d < DD; ++d) dg += (sEdges[n*DD + d] != -1) ? 1 : 0;
      sDeg[n] = dg;
    } else {
      sSorted[n] = -1;                   // pad entries 60..63
    }
    const u64 below = (lane == 63) ? ~0ull >> 1 : ((1ull << lane) - 1);
    int rs = 0, np = 0;
    #pragma unroll 1
    for (int d = 0; d < 7; ++d) {
      u64 m = __ballot(dg == d);
      int cnt = (int)__popcll(m);
      if (dg == d) sSorted[rs + (int)__popcll(m & below)] = n;
      if (lane == 0 && cnt > 0) {
        const int r1 = rs + cnt;
        for (int mt = rs >> 4; mt < ((r1 + 15) >> 4); ++mt) {
          sPairD[np] = d; sPairM[np] = mt; ++np;
        }
      }
      rs += cnt;
    }
    if (lane == 0) sNP = np;
  }
  __syncthreads();
  const int nP = sNP;

  // ---- P1: A1 build — scalar odd-stride-37 gathers, hi/lo out ----
  {
    const int row = t >> 3, c = t & 7;     // 512 units exactly
    const int node = sSorted[row];
    float acc[8] = {0,0,0,0,0,0,0,0};
    if (node >= 0) {
      int e[DD];
      #pragma unroll
      for (int d = 0; d < DD; ++d) e[d] = sEdges[node*DD + d];
      #pragma unroll
      for (int j = 0; j < 8; ++j) {
        int k = c*8 + j;
        float v = 0.f;
        if (k < AF) {
          v = sAtoms[node*AF + k];
          #pragma unroll
          for (int d = 0; d < DD; ++d) if (e[d] >= 0) v += sAtoms[e[d]*AF + k];
        } else if (k < AF + BFD) {
          v = sBsum[node*BFD + (k - AF)];
        }
        acc[j] = v;
      }
    }
    uint4 hi, lo; split8(acc, hi, lo);
    *(uint4*)(&sFA[row*FASTR + c*8]) = hi;
    *(uint4*)(&sFA[(64 + row)*FASTR + c*8]) = lo;
  }
  __syncthreads();

  // ---- P2: conv1 MFMA -> X1 (sXa fp32) ----
  conv_mfma<KS1>(ws, b1, sFA, sXa, sSorted, sDeg, sPairD, sPairM, nP, wv, lane);
  __syncthreads();

  // ---- P3: pool1 IN PLACE: X2 = max(self, nbrs)(X1) * (deg>0) ----
  {
    float4 m[4];
    #pragma unroll
    for (int j = 0; j < 4; ++j) {
      int idx = t + j*T;
      if (idx < NN*32) {
        int n = idx >> 5, c = idx & 31;
        float4 v = {0.f, 0.f, 0.f, 0.f};
        if (sDeg[n] > 0) {
          v = *(const float4*)(&sXa[n*XSTR + c*4]);
          #pragma unroll
          for (int d = 0; d < DD; ++d) {
            int e = sEdges[n*DD + d];
            if (e >= 0) {
              float4 u = *(const float4*)(&sXa[e*XSTR + c*4]);
              v.x = fmaxf(v.x, u.x); v.y = fmaxf(v.y, u.y);
              v.z = fmaxf(v.z, u.z); v.w = fmaxf(v.w, u.w);
            }
          }
        }
        m[j] = v;
      }
    }
    __syncthreads();
    #pragma unroll
    for (int j = 0; j < 4; ++j) {
      int idx = t + j*T;
      if (idx < NN*32) {
        int n = idx >> 5, c = idx & 31;
        *(float4*)(&sXa[n*XSTR + c*4]) = m[j];
      }
    }
  }
  __syncthreads();

  // ---- P4: A2 build — feat2 = (self+nbr sums of X2 | bsum | pad), hi/lo ----
  for (int unit = t; unit < 64*16; unit += T) {
    int row = unit >> 4, c = unit & 15;
    int node = sSorted[row];
    float acc[8] = {0,0,0,0,0,0,0,0};
    if (node >= 0) {
      *(float4*)(&acc[0]) = *(const float4*)(&sXa[node*XSTR + c*8]);
      *(float4*)(&acc[4]) = *(const float4*)(&sXa[node*XSTR + c*8 + 4]);
      #pragma unroll
      for (int d = 0; d < DD; ++d) {
        int e = sEdges[node*DD + d];
        if (e >= 0) {
          float4 u0 = *(const float4*)(&sXa[e*XSTR + c*8]);
          float4 u1 = *(const float4*)(&sXa[e*XSTR + c*8 + 4]);
          acc[0]+=u0.x; acc[1]+=u0.y; acc[2]+=u0.z; acc[3]+=u0.w;
          acc[4]+=u1.x; acc[5]+=u1.y; acc[6]+=u1.z; acc[7]+=u1.w;
        }
      }
    }
    uint4 hi, lo; split8(acc, hi, lo);
    *(uint4*)(&sFA[row*FASTR + c*8]) = hi;
    *(uint4*)(&sFA[(64 + row)*FASTR + c*8]) = lo;
  }
  // K-tail k=128..159 (bsum | zeros) — written ONCE; P6 leaves it untouched so
  // A3 (gout) reuses it (bsum is layer-invariant).
  if (t < 256) {
    int row = t >> 2, part = t & 3;
    uint4 hi = {0,0,0,0}, lo = {0,0,0,0};
    if (part == 0) {
      int node = sSorted[row];
      float acc[8] = {0,0,0,0,0,0,0,0};
      if (node >= 0) {
        #pragma unroll
        for (int j = 0; j < BFD; ++j) acc[j] = sBsum[node*BFD + j];
      }
      split8(acc, hi, lo);
    }
    *(uint4*)(&sFA[row*FASTR + 128 + part*8]) = hi;
    *(uint4*)(&sFA[(64 + row)*FASTR + 128 + part*8]) = lo;
  }
  __syncthreads();

  // ---- P5: conv2 MFMA -> x3 (sXa) ----
  conv_mfma<KS2>(ws + W2T_OFF, b2, sFA, sXa, sSorted, sDeg, sPairD, sPairM, nP, wv, lane);
  __syncthreads();

  // ---- Hoist gout B-fragments NOW (10 KB global loads) so their L2 latency
  // hides behind P6's VALU work instead of stalling P8. ~40 extra VGPRs. ----
  v8s g_bh[KS2], g_bl[KS2];
  {
    const int nt = wv;
    #pragma unroll
    for (int ks = 0; ks < KS2; ++ks) {
      const size_t ub = WOT_OFF + ((size_t)(nt*KS2 + ks))*512;
      g_bh[ks] = ((const v8s*)(ws + ub))[lane];
      g_bl[ks] = ((const v8s*)(ws + LO_OFF + ub))[lane];
    }
  }

  // ---- P6+P7 FUSED: x4 = max(self,nbrs)(x3)*(deg>0) -> A3 hi/lo (cols 0..127) ----
  for (int unit = t; unit < 64*16; unit += T) {
    int row = unit >> 4, c = unit & 15;
    int node = sSorted[row];
    float acc[8] = {0,0,0,0,0,0,0,0};
    if (node >= 0 && sDeg[node] > 0) {
      float4 a0 = *(const float4*)(&sXa[node*XSTR + c*8]);
      float4 a1 = *(const float4*)(&sXa[node*XSTR + c*8 + 4]);
      #pragma unroll
      for (int d = 0; d < DD; ++d) {
        int e = sEdges[node*DD + d];
        if (e >= 0) {
          float4 u0 = *(const float4*)(&sXa[e*XSTR + c*8]);
          float4 u1 = *(const float4*)(&sXa[e*XSTR + c*8 + 4]);
          a0.x = fmaxf(a0.x, u0.x); a0.y = fmaxf(a0.y, u0.y);
          a0.z = fmaxf(a0.z, u0.z); a0.w = fmaxf(a0.w, u0.w);
          a1.x = fmaxf(a1.x, u1.x); a1.y = fmaxf(a1.y, u1.y);
          a1.z = fmaxf(a1.z, u1.z); a1.w = fmaxf(a1.w, u1.w);
        }
      }
      acc[0]=a0.x; acc[1]=a0.y; acc[2]=a0.z; acc[3]=a0.w;
      acc[4]=a1.x; acc[5]=a1.y; acc[6]=a1.z; acc[7]=a1.w;
    }
    uint4 hi, lo; split8(acc, hi, lo);
    *(uint4*)(&sFA[row*FASTR + c*8]) = hi;
    *(uint4*)(&sFA[(64 + row)*FASTR + c*8]) = lo;
  }
  __syncthreads();

  // ---- P8: gout MFMA: wave wv <-> n-tile wv; B already in regs (hoisted) ----
  {
    const int nt = wv, n16 = lane & 15, q = lane >> 4;
    const int h = nt*16 + n16;
    const float bb = bo[h];
    float part = 0.f;
    #pragma unroll 2
    for (int mt = 0; mt < 4; ++mt) {
      const int row = mt*16 + n16;
      v4f acc = {0.f, 0.f, 0.f, 0.f};
      #pragma unroll
      for (int ks = 0; ks < KS2; ++ks) {
        v8s ah = *(const v8s*)(&sFA[row*FASTR + ks*32 + q*8]);
        v8s al = *(const v8s*)(&sFA[(64 + row)*FASTR + ks*32 + q*8]);
        acc = __builtin_amdgcn_mfma_f32_16x16x32_bf16(ah, g_bh[ks], acc, 0, 0, 0);
        acc = __builtin_amdgcn_mfma_f32_16x16x32_bf16(al, g_bh[ks], acc, 0, 0, 0);
        acc = __builtin_amdgcn_mfma_f32_16x16x32_bf16(ah, g_bl[ks], acc, 0, 0, 0);
      }
      #pragma unroll
      for (int r = 0; r < 4; ++r) {
        int node = sSorted[mt*16 + q*4 + r];
        if (node >= 0 && sDeg[node] > 0) part += fast_tanh(acc[r] + bb);
      }
    }
    part += __shfl_xor(part, 16);
    part += __shfl_xor(part, 32);
    if (lane < 16) sPart[h] = part;
  }
  __syncthreads();

  // ---- P9: final FC + sigmoid (96 threads, 16 FMAs each, reduce) ----
  if (t < 96) {
    const int c = t >> 3, s = t & 7;
    float acc = 0.f;
    #pragma unroll
    for (int i = 0; i < 16; ++i) {
      int ii = s*16 + i;
      acc = fmaf(sPart[ii], Wfc[ii*CC + c], acc);
    }
    sRed[t] = acc;
  }
  __syncthreads();
  if (t < CC) {
    float acc = bfc[t];
    #pragma unroll
    for (int s = 0; s < 8; ++s) acc += sRed[t*8 + s];
    out[b*CC + t] = 1.f / (1.f + __expf(-acc));
  }
}

extern "C" void kernel_launch(void* const* d_in, const int* in_sizes, int n_in,
                              void* d_out, int out_size, void* d_ws, size_t ws_size,
                              hipStream_t stream) {
  const float* atoms = (const float*)d_in[0];
  const float* bonds = (const float*)d_in[1];
  const int*   edges = (const int*)d_in[2];
  const float* W1  = (const float*)d_in[3];
  const float* b1  = (const float*)d_in[4];
  const float* W2  = (const float*)d_in[5];
  const float* b2  = (const float*)d_in[6];
  const float* Wo  = (const float*)d_in[7];
  const float* bo  = (const float*)d_in[8];
  const float* Wfc = (const float*)d_in[9];
  const float* bfc = (const float*)d_in[10];
  float* out = (float*)d_out;
  u16* ws = (u16*)d_ws;

  prep_kernel<<<(TOT_UNITS*512 + 255)/256, 256, 0, stream>>>(W1, W2, Wo, ws);
  ngfp_kernel<<<NB, T, 0, stream>>>(atoms, bonds, edges, b1, b2, bo, Wfc, bfc, ws, out);
}